// Round 1
// baseline (967.638 us; speedup 1.0000x reference)
//
#include <hip/hip_runtime.h>
#include <cstdint>
#include <cstddef>

// ---------------------------------------------------------------------------
// Types / helpers
// ---------------------------------------------------------------------------
using bf16x8 = __attribute__((ext_vector_type(8))) __bf16;
using f32x4  = __attribute__((ext_vector_type(4))) float;

__device__ __forceinline__ unsigned short f2bf(float f) {
  union { float f; uint32_t u; } v; v.f = f;
  uint32_t r = (v.u + 0x7fffu + ((v.u >> 16) & 1u)) >> 16;
  return (unsigned short)r;
}

__device__ __forceinline__ float waveRed(float v) {
#pragma unroll
  for (int m = 32; m >= 1; m >>= 1) v += __shfl_xor(v, m, 64);
  return v;
}

// async global->LDS, 16B per lane. LDS dest must be wave-uniform base + lane*16.
__device__ __forceinline__ void gload16(const void* g, void* l) {
  __builtin_amdgcn_global_load_lds(
      (__attribute__((address_space(1))) uint32_t*)(uintptr_t)g,
      (__attribute__((address_space(3))) uint32_t*)(uint32_t*)l,
      16, 0, 0);
}

// ---------------------------------------------------------------------------
// Small utility kernels
// ---------------------------------------------------------------------------
__global__ void zero_k(float* __restrict__ p, int n) {
  for (int i = blockIdx.x * 256 + threadIdx.x; i < n; i += gridDim.x * 256) p[i] = 0.f;
}

__global__ void cvtx_k(const float4* __restrict__ x, ushort4* __restrict__ xb,
                       float* __restrict__ sumsq, int n4) {
  float s = 0.f;
  for (int i = blockIdx.x * 256 + threadIdx.x; i < n4; i += gridDim.x * 256) {
    float4 v = x[i];
    ushort4 o;
    o.x = f2bf(v.x); o.y = f2bf(v.y); o.z = f2bf(v.z); o.w = f2bf(v.w);
    xb[i] = o;
    s += v.x * v.x + v.y * v.y + v.z * v.z + v.w * v.w;
  }
  s = waveRed(s);
  if ((threadIdx.x & 63) == 0) atomicAdd(sumsq, s);
}

__global__ void cvtw_k(const float4* __restrict__ in, ushort4* __restrict__ out, int n4) {
  for (int i = blockIdx.x * 256 + threadIdx.x; i < n4; i += gridDim.x * 256) {
    float4 v = in[i];
    ushort4 o;
    o.x = f2bf(v.x); o.y = f2bf(v.y); o.z = f2bf(v.z); o.w = f2bf(v.w);
    out[i] = o;
  }
}

// out[c*R + r] = f2bf(in[r*C + c]);  in: R x C fp32, out: C x R bf16
__global__ void trf_k(const float* __restrict__ in, unsigned short* __restrict__ out,
                      int R, int C, int n) {
  for (int o = blockIdx.x * 256 + threadIdx.x; o < n; o += gridDim.x * 256) {
    int c = o / R, r = o - c * R;
    out[o] = f2bf(in[(size_t)r * C + c]);
  }
}

// bf16 transpose: out[c*R + r] = in[r*C + c]
__global__ void trb_k(const unsigned short* __restrict__ in, unsigned short* __restrict__ out,
                      int R, int C, int n) {
  for (int o = blockIdx.x * 256 + threadIdx.x; o < n; o += gridDim.x * 256) {
    int c = o / R, r = o - c * R;
    out[o] = in[(size_t)r * C + c];
  }
}

__global__ void count_k(const int* __restrict__ lab, int* __restrict__ counts, int n) {
  for (int i = blockIdx.x * 256 + threadIdx.x; i < n; i += gridDim.x * 256)
    atomicAdd(&counts[lab[i]], 1);
}

__global__ void prefix_k(const int* __restrict__ counts, int* __restrict__ offsets,
                         int* __restrict__ cursor, int nc) {
  if (blockIdx.x == 0 && threadIdx.x == 0) {
    int o = 0;
    for (int c = 0; c < nc; ++c) { offsets[c] = o; cursor[c] = o; o += counts[c]; }
  }
}

__global__ void scatter_k(const int* __restrict__ lab, int* __restrict__ cursor,
                          int* __restrict__ buckets, int n) {
  for (int i = blockIdx.x * 256 + threadIdx.x; i < n; i += gridDim.x * 256) {
    int pos = atomicAdd(&cursor[lab[i]], 1);
    buckets[pos] = i;
  }
}

// one block per class: sum rows, then atomicAdd(||sums||^2 / count)
__global__ __launch_bounds__(256) void center_k(const float* __restrict__ x,
    const int* __restrict__ buckets, const int* __restrict__ offsets,
    const int* __restrict__ counts, float* __restrict__ out, int D) {
  int c = blockIdx.x;
  int cnt = counts[c];
  if (cnt == 0) return;
  int beg = offsets[c];
  float ssq = 0.f;
  for (int d2 = threadIdx.x; d2 < (D >> 1); d2 += 256) {
    float sx = 0.f, sy = 0.f;
    for (int r = 0; r < cnt; ++r) {
      int row = buckets[beg + r];
      float2 v = ((const float2*)(x + (size_t)row * D))[d2];
      sx += v.x; sy += v.y;
    }
    ssq += sx * sx + sy * sy;
  }
  ssq = waveRed(ssq);
  __shared__ float red[4];
  if ((threadIdx.x & 63) == 0) red[threadIdx.x >> 6] = ssq;
  __syncthreads();
  if (threadIdx.x == 0)
    atomicAdd(out, (red[0] + red[1] + red[2] + red[3]) / (float)cnt);
}

__global__ void copy_k(const float* __restrict__ in, float* __restrict__ out, int n) {
  for (int i = blockIdx.x * 256 + threadIdx.x; i < n; i += gridDim.x * 256) out[i] = in[i];
}

// vout[row] = badd[row] + sum_k W[row,K] vin[k]; one block per row
__global__ __launch_bounds__(256) void matvec_k(const float* __restrict__ W,
    const float* __restrict__ vin, const float* __restrict__ badd,
    float* __restrict__ vout, int K) {
  int row = blockIdx.x;
  float s = 0.f;
  for (int k = threadIdx.x; k < K; k += 256) s += W[(size_t)row * K + k] * vin[k];
  s = waveRed(s);
  __shared__ float red[4];
  if ((threadIdx.x & 63) == 0) red[threadIdx.x >> 6] = s;
  __syncthreads();
  if (threadIdx.x == 0) vout[row] = red[0] + red[1] + red[2] + red[3] + badd[row];
}

// ---------------------------------------------------------------------------
// bf16 MFMA GEMM: C[M,N] = A[M,K] @ B[N,K]^T   (both row-major, K contiguous)
// 128x128 tile, BK=32, 256 threads (4 waves, each 64x64 via 4x4 16x16 frags).
// CE=true: fused cross-entropy epilogue (expsum/picked atomics, no C store).
// CE=false: store C as bf16 row-major.
// ---------------------------------------------------------------------------
#define BM 128
#define BN 128
#define BKK 32

template <bool CE>
__global__ __launch_bounds__(256) void gemm_bt(
    const unsigned short* __restrict__ A, const unsigned short* __restrict__ Bm,
    int M, int N, int K,
    const float* __restrict__ bias, const int* __restrict__ labels,
    float* __restrict__ expsum, float* __restrict__ picked,
    unsigned short* __restrict__ Cout, int Bsz, int lvl0n, int lvl1n) {
  __shared__ __align__(16) unsigned short As[BM * BKK];
  __shared__ __align__(16) unsigned short Bs[BN * BKK];
  const int tid = threadIdx.x;
  const int lane = tid & 63;
  const int wave = tid >> 6;
  const int lane16 = lane & 15;
  const int quad = lane >> 4;
  const int wm = (wave >> 1) * 64;
  const int wn = (wave & 1) * 64;
  const int m0 = blockIdx.y * BM;
  const int n0 = blockIdx.x * BN;

  f32x4 acc[4][4] = {};

  const int srow = tid >> 2;          // 0..63 : staging row within tile-half
  const int skof = (tid & 3) * 8;     // element offset in k
  const unsigned short* Ab = A + (size_t)(m0 + srow) * K + skof;
  const unsigned short* Bb = Bm + (size_t)(n0 + srow) * K + skof;
  const size_t rstep = (size_t)64 * K;

  for (int kt = 0; kt < K; kt += BKK) {
    gload16(Ab + kt,         &As[tid * 8]);
    gload16(Ab + rstep + kt, &As[2048 + tid * 8]);
    gload16(Bb + kt,         &Bs[tid * 8]);
    gload16(Bb + rstep + kt, &Bs[2048 + tid * 8]);
    __syncthreads();
    bf16x8 af[4], bfv[4];
#pragma unroll
    for (int i = 0; i < 4; ++i)
      af[i] = *(const bf16x8*)&As[(wm + i * 16 + lane16) * BKK + quad * 8];
#pragma unroll
    for (int j = 0; j < 4; ++j)
      bfv[j] = *(const bf16x8*)&Bs[(wn + j * 16 + lane16) * BKK + quad * 8];
#pragma unroll
    for (int i = 0; i < 4; ++i)
#pragma unroll
      for (int j = 0; j < 4; ++j)
        acc[i][j] = __builtin_amdgcn_mfma_f32_16x16x32_bf16(af[i], bfv[j], acc[i][j], 0, 0, 0);
    __syncthreads();
  }

  if (CE) {
    // level decode from block's column range (level boundaries are 128-aligned)
    int lvl, cbase;
    if (n0 < lvl0n)              { lvl = 0; cbase = 0; }
    else if (n0 < lvl0n + lvl1n) { lvl = 1; cbase = lvl0n; }
    else                         { lvl = 2; cbase = lvl0n + lvl1n; }
    float bj[4];
#pragma unroll
    for (int j = 0; j < 4; ++j) bj[j] = bias[n0 + wn + j * 16 + lane16];
    float* es = expsum + (size_t)lvl * Bsz;
    float* pk = picked + (size_t)lvl * Bsz;
#pragma unroll
    for (int i = 0; i < 4; ++i) {
#pragma unroll
      for (int r = 0; r < 4; ++r) {
        const int rowg = m0 + wm + i * 16 + quad * 4 + r;
        const int lab = labels[rowg];
        float part = 0.f;
#pragma unroll
        for (int j = 0; j < 4; ++j) {
          const float v = acc[i][j][r] + bj[j];
          part += __expf(v);
          if (n0 + wn + j * 16 + lane16 - cbase == lab) atomicAdd(&pk[rowg], v);
        }
        part += __shfl_xor(part, 1, 64);
        part += __shfl_xor(part, 2, 64);
        part += __shfl_xor(part, 4, 64);
        part += __shfl_xor(part, 8, 64);
        if (lane16 == 0) atomicAdd(&es[rowg], part);
      }
    }
  } else {
#pragma unroll
    for (int i = 0; i < 4; ++i)
#pragma unroll
      for (int r = 0; r < 4; ++r) {
        const int rowg = m0 + wm + i * 16 + quad * 4 + r;
#pragma unroll
        for (int j = 0; j < 4; ++j) {
          const int colg = n0 + wn + j * 16 + lane16;
          Cout[(size_t)rowg * N + colg] = f2bf(acc[i][j][r]);
        }
      }
  }
}

// per-row nll over 3 levels, accumulate sums into nll[0..2]
__global__ void nll_k(const float* __restrict__ es, const float* __restrict__ pk,
                      float* __restrict__ nll, int B) {
  float l0 = 0.f, l1 = 0.f, l2 = 0.f;
  for (int i = blockIdx.x * 256 + threadIdx.x; i < B; i += gridDim.x * 256) {
    l0 += __logf(es[i])         - pk[i];
    l1 += __logf(es[i + B])     - pk[i + B];
    l2 += __logf(es[i + 2 * B]) - pk[i + 2 * B];
  }
  l0 = waveRed(l0); l1 = waveRed(l1); l2 = waveRed(l2);
  if ((threadIdx.x & 63) == 0) {
    atomicAdd(&nll[0], l0);
    atomicAdd(&nll[1], l1);
    atomicAdd(&nll[2], l2);
  }
}

// scal: [0]=sumsq_x [1]=sum ||sums_c||^2/n_c  [2..4]=nll sums
__global__ void fin_k(const float* __restrict__ scal, const float* __restrict__ lam,
                      float* __restrict__ out, float invB) {
  if (threadIdx.x == 0 && blockIdx.x == 0)
    out[0] = lam[0] * (scal[0] - scal[1]) +
             (lam[1] * scal[2] + lam[2] * scal[3] + lam[3] * scal[4]) * invB;
}

// ---------------------------------------------------------------------------
// Launch
// ---------------------------------------------------------------------------
extern "C" void kernel_launch(void* const* d_in, const int* in_sizes, int n_in,
                              void* d_out, int out_size, void* d_ws, size_t ws_size,
                              hipStream_t stream) {
  const float* x   = (const float*)d_in[0];
  const float* W0  = (const float*)d_in[1];
  const float* b0  = (const float*)d_in[2];
  const float* W1  = (const float*)d_in[3];
  const float* b1  = (const float*)d_in[4];
  const float* W2  = (const float*)d_in[5];
  const float* b2  = (const float*)d_in[6];
  const float* lam = (const float*)d_in[7];
  const int*   lab = (const int*)d_in[8];

  const int Bsz = in_sizes[8];         // 65536
  const int D   = in_sizes[0] / Bsz;   // 512
  const int N0  = in_sizes[2];         // 2048
  const int N1  = in_sizes[4];         // 1024
  const int N2  = in_sizes[6];         // 512
  const int Ncat = N0 + N1 + N2;       // 3584
  const int NCLS = 512;                // NUM_CLASSES

  char* w = (char*)d_ws;
  size_t off = 0;
  auto alloc = [&](size_t bytes) -> void* {
    void* p = w + off;
    off += (bytes + 255) & ~(size_t)255;
    return p;
  };

  unsigned short* xb   = (unsigned short*)alloc((size_t)Bsz * D * 2);
  // Bcat = [W0b | M1 | M2] contiguous (all slot sizes are multiples of 256B)
  unsigned short* Bcat = (unsigned short*)alloc((size_t)Ncat * D * 2);
  unsigned short* W0b  = Bcat;
  unsigned short* M1   = Bcat + (size_t)N0 * D;
  unsigned short* M2   = Bcat + (size_t)(N0 + N1) * D;
  unsigned short* W0t  = (unsigned short*)alloc((size_t)D * N0 * 2);
  unsigned short* W1b  = (unsigned short*)alloc((size_t)N1 * N0 * 2);
  unsigned short* W2b  = (unsigned short*)alloc((size_t)N2 * N1 * 2);
  unsigned short* M1t  = (unsigned short*)alloc((size_t)D * N1 * 2);
  float* biascat = (float*)alloc((size_t)Ncat * 4);
  int* offsets = (int*)alloc(NCLS * 4);
  int* cursor  = (int*)alloc(NCLS * 4);
  int* buckets = (int*)alloc((size_t)Bsz * 4);
  // zero region: counts | scal(8f) | expsum(3B) | picked(3B)
  size_t zbytes = (size_t)NCLS * 4 + 256 + (size_t)3 * Bsz * 4 * 2;
  char* zr = (char*)alloc(zbytes);
  int*   counts = (int*)zr;
  float* scal   = (float*)(zr + NCLS * 4);
  float* expsum = (float*)(zr + NCLS * 4 + 256);
  float* picked = expsum + (size_t)3 * Bsz;
  (void)ws_size; (void)n_in; (void)out_size;

  const int zwords = (int)(zbytes / 4);
  zero_k<<<dim3((zwords + 255) / 256), dim3(256), 0, stream>>>((float*)zr, zwords);

  // x -> bf16 + sum of squares
  const int n4x = Bsz * D / 4;
  cvtx_k<<<dim3(1024), dim3(256), 0, stream>>>((const float4*)x, (ushort4*)xb, &scal[0], n4x);

  // weight conversions
  cvtw_k<<<dim3((N0 * D / 4 + 255) / 256), dim3(256), 0, stream>>>((const float4*)W0, (ushort4*)W0b, N0 * D / 4);
  cvtw_k<<<dim3((N1 * N0 / 4 + 255) / 256), dim3(256), 0, stream>>>((const float4*)W1, (ushort4*)W1b, N1 * N0 / 4);
  cvtw_k<<<dim3((N2 * N1 / 4 + 255) / 256), dim3(256), 0, stream>>>((const float4*)W2, (ushort4*)W2b, N2 * N1 / 4);
  // W0^T (D x N0) bf16, from fp32 W0
  trf_k<<<dim3(4096), dim3(256), 0, stream>>>(W0, W0t, N0, D, N0 * D);

  // center-loss bucketing
  count_k<<<dim3(256), dim3(256), 0, stream>>>(lab, counts, Bsz);
  prefix_k<<<dim3(1), dim3(64), 0, stream>>>(counts, offsets, cursor, NCLS);
  scatter_k<<<dim3(256), dim3(256), 0, stream>>>(lab, cursor, buckets, Bsz);
  center_k<<<dim3(NCLS), dim3(256), 0, stream>>>(x, buckets, offsets, counts, &scal[1], D);

  // collapsed biases: biascat = [b0 | b1 + W1 b0 | b2 + W2 c1]
  copy_k<<<dim3(8), dim3(256), 0, stream>>>(b0, biascat, N0);
  matvec_k<<<dim3(N1), dim3(256), 0, stream>>>(W1, b0, b1, biascat + N0, N0);
  matvec_k<<<dim3(N2), dim3(256), 0, stream>>>(W2, biascat + N0, b2, biascat + N0 + N1, N1);

  // M1 = W1 @ W0  (N1 x D), via A=W1b (N1 x N0), B=W0t (D x N0)
  gemm_bt<false><<<dim3(D / BN, N1 / BM), dim3(256), 0, stream>>>(
      W1b, W0t, N1, D, N0, nullptr, nullptr, nullptr, nullptr, M1, Bsz, N0, N1);
  // M1t = M1^T (D x N1)
  trb_k<<<dim3(2048), dim3(256), 0, stream>>>(M1, M1t, N1, D, N1 * D);
  // M2 = W2 @ M1 (N2 x D), via A=W2b (N2 x N1), B=M1t (D x N1)
  gemm_bt<false><<<dim3(D / BN, N2 / BM), dim3(256), 0, stream>>>(
      W2b, M1t, N2, D, N1, nullptr, nullptr, nullptr, nullptr, M2, Bsz, N0, N1);

  // fused logits + CE for all three levels: A=xb (Bsz x D), B=Bcat (Ncat x D)
  gemm_bt<true><<<dim3(Ncat / BN, Bsz / BM), dim3(256), 0, stream>>>(
      xb, Bcat, Bsz, Ncat, D, biascat, lab, expsum, picked, nullptr, Bsz, N0, N1);

  // reduce nll and finalize
  nll_k<<<dim3(256), dim3(256), 0, stream>>>(expsum, picked, &scal[2], Bsz);
  fin_k<<<dim3(1), dim3(64), 0, stream>>>(scal, lam, (float*)d_out, 1.f / (float)Bsz);
}